// Round 2
// baseline (1116.849 us; speedup 1.0000x reference)
//
#include <hip/hip_runtime.h>
#include <hip/hip_bf16.h>
#include <stdint.h>

// ---------------------------------------------------------------------------
// MultiHeadAttentionT: B=16, L=1024, D_MODEL=19, H=8 heads x 64 = 512
// out tuple: out[16,1024,19] | attn[16,8,1024,1024] | residual[16,1024,19]
// ---------------------------------------------------------------------------

#define LQ 1024
#define DM 19
#define NHEAD 8
#define DH 64
#define HT 512
#define NBATCH 16

using f32x4  = __attribute__((ext_vector_type(4))) float;
using bf16x8 = __attribute__((ext_vector_type(8))) __bf16;
using ushort_t = unsigned short;

// 1/sqrt(512/9) = 3/sqrt(512)
#define INV_SCALE 0.13258252147247766f

__device__ __forceinline__ ushort_t f2bf(float f) {
  union { float f; unsigned u; } v; v.f = f;
  unsigned r = v.u + 0x7FFFu + ((v.u >> 16) & 1u);
  return (ushort_t)(r >> 16);
}

// ---------------------------------------------------------------------------
// Mask dtype detector: numpy bool (1 byte/elem) vs promoted int32 (4 bytes).
// int32 little-endian 0/1 values have zero bytes at offsets i%4!=0.
// bool layout has ~50% nonzero bytes everywhere. flag=1 -> byte layout.
// ---------------------------------------------------------------------------
__global__ void k_detect(const unsigned char* __restrict__ m, int* __restrict__ flag) {
  __shared__ int any;
  if (threadIdx.x == 0) any = 0;
  __syncthreads();
  int loc = 0;
  for (int i = threadIdx.x; i < 16384; i += 256)
    if (i & 3) loc |= m[i];
  if (loc) any = 1;
  __syncthreads();
  if (threadIdx.x == 0) *flag = (any != 0);
}

// ---------------------------------------------------------------------------
// Projections: q = QWq+bq, k = KWk+bk, v = VWv+bv  -> bf16
// qb, kb laid out [bh][l][64]; v transposed to vT [bh][64][l] so that the PV
// MFMA B-fragment (8 contiguous k per lane) is a 16B contiguous global load.
// grid 2048 = 128 bh * 16 ltiles(64 rows), block 256.
// ---------------------------------------------------------------------------
__global__ __launch_bounds__(256, 4) void k_proj(
    const float* __restrict__ Q, const float* __restrict__ K, const float* __restrict__ V,
    const float* __restrict__ Wq, const float* __restrict__ bq,
    const float* __restrict__ Wk, const float* __restrict__ bk,
    const float* __restrict__ Wv, const float* __restrict__ bv,
    ushort_t* __restrict__ qb, ushort_t* __restrict__ kb, ushort_t* __restrict__ vT) {
  const int bid = blockIdx.x;
  const int bh = bid >> 4;          // 0..127
  const int lt = (bid & 15) * 64;   // row tile base
  const int b  = bh >> 3;
  const int h  = bh & 7;
  const int t  = threadIdx.x;

  __shared__ float xs[3][64 * DM];     // x rows for Q,K,V inputs
  __shared__ float wsh[3][DM * DH];    // weight columns for this head
  __shared__ ushort_t vt[64 * 73];     // v tile for transposed write (+pad)

  const int rowbase = (b * LQ + lt) * DM;
  for (int i = t; i < 64 * DM; i += 256) {
    xs[0][i] = Q[rowbase + i];
    xs[1][i] = K[rowbase + i];
    xs[2][i] = V[rowbase + i];
  }
  for (int i = t; i < DM * DH; i += 256) {
    int j = i >> 6, d = i & 63;
    wsh[0][i] = Wq[j * HT + h * DH + d];
    wsh[1][i] = Wk[j * HT + h * DH + d];
    wsh[2][i] = Wv[j * HT + h * DH + d];
  }
  __syncthreads();

  const int d = t & 63;
  const int w = t >> 6;
  const float bqv = bq[h * DH + d], bkv = bk[h * DH + d], bvv = bv[h * DH + d];
  const size_t outb = ((size_t)bh * LQ + lt) * DH;

  for (int it = 0; it < 16; ++it) {
    const int r = it * 4 + w;        // wave-uniform row -> broadcast LDS reads
    float aq = bqv, ak = bkv, av = bvv;
#pragma unroll
    for (int j = 0; j < DM; ++j) {
      const float xq = xs[0][r * DM + j], xk = xs[1][r * DM + j], xv = xs[2][r * DM + j];
      aq += xq * wsh[0][j * DH + d];
      ak += xk * wsh[1][j * DH + d];
      av += xv * wsh[2][j * DH + d];
    }
    qb[outb + (size_t)r * DH + d] = f2bf(aq);
    kb[outb + (size_t)r * DH + d] = f2bf(ak);
    vt[r * 73 + d] = f2bf(av);
  }
  __syncthreads();

  const size_t vbase = (size_t)bh * DH * LQ + lt;   // vT[(bh*64+d)*1024 + lt + r]
  for (int it = 0; it < 16; ++it) {
    const int e = t + 256 * it;
    const int dd = e >> 6, rr = e & 63;
    vT[vbase + (size_t)dd * LQ + rr] = vt[rr * 73 + dd];
  }
}

// ---------------------------------------------------------------------------
// Fused attention: per block (bh, 16 q-rows). 4 waves, wave w owns k-span
// [256w, 256w+256). QK^T via mfma 16x16x32 bf16, mask+softmax in regs
// (shfl over 16-lane groups + LDS cross-wave combine), normalized attn written
// nontemporally, P staged to LDS (bf16) for the PV MFMA, context partials
// summed through LDS and scaled by 1/rowsum.
// MFMA fragment layouts (gfx950, m89/m92-consistent):
//   A[16][32]: lane l -> row l&15,        k = 8*(l>>4)+i (i=0..7 contiguous)
//   B[32][16]: lane l -> col l&15,        k = 8*(l>>4)+i
//   C[16][16]: lane l -> col l&15,        row = 4*(l>>4)+reg
// ---------------------------------------------------------------------------
__global__ __launch_bounds__(256, 2) void k_attn(
    const ushort_t* __restrict__ qb, const ushort_t* __restrict__ kbuf,
    const ushort_t* __restrict__ vT, const void* __restrict__ maskp,
    const int* __restrict__ flagp,
    float* __restrict__ attn, float* __restrict__ ctx) {
  const int bid = blockIdx.x;
  const int bh  = bid >> 6;
  const int qt  = bid & 63;
  const int bidx = bh >> 3;   // batch
  const int h    = bh & 7;
  const int t    = threadIdx.x;
  const int w    = t >> 6;
  const int lane = t & 63;
  const int g    = lane >> 4;
  const int c    = lane & 15;
  const int q0   = qt * 16;
  const int k0   = w * 256;

  __shared__ ushort_t pbuf[4][16][274];   // per-wave P tile (bf16, stride 548B)
  __shared__ float c2s[4][16][64];        // per-wave context partials
  __shared__ float wmax[4][16];
  __shared__ float wsum[4][16];

  // ---- Q A-fragments (row = q0+c, k-dim = head dim) ----
  const ushort_t* qrow = qb + ((size_t)(bh * LQ + q0 + c)) * DH + 8 * g;
  const bf16x8 aq0 = *(const bf16x8*)(qrow);
  const bf16x8 aq1 = *(const bf16x8*)(qrow + 32);

  f32x4 acc[16];
#pragma unroll
  for (int f = 0; f < 16; ++f) acc[f] = (f32x4){0.f, 0.f, 0.f, 0.f};

  // ---- S = Q K^T over this wave's 256-key span ----
#pragma unroll
  for (int f = 0; f < 16; ++f) {
    const ushort_t* krow = kbuf + ((size_t)(bh * LQ + k0 + f * 16 + c)) * DH + 8 * g;
    const bf16x8 b0 = *(const bf16x8*)(krow);
    const bf16x8 b1 = *(const bf16x8*)(krow + 32);
    acc[f] = __builtin_amdgcn_mfma_f32_16x16x32_bf16(aq0, b0, acc[f], 0, 0, 0);
    acc[f] = __builtin_amdgcn_mfma_f32_16x16x32_bf16(aq1, b1, acc[f], 0, 0, 0);
  }

  // ---- scale + mask + row max ----
  const int fl = *flagp;                      // uniform
  const unsigned char* mB = (const unsigned char*)maskp;
  const int* mI = (const int*)maskp;

  size_t mbase[4];
#pragma unroll
  for (int r = 0; r < 4; ++r)
    mbase[r] = ((size_t)(bidx * LQ + q0 + 4 * g + r)) * LQ + k0 + c;

  float mx[4] = {-3.0e38f, -3.0e38f, -3.0e38f, -3.0e38f};
#pragma unroll
  for (int f = 0; f < 16; ++f) {
#pragma unroll
    for (int r = 0; r < 4; ++r) {
      const size_t mi = mbase[r] + f * 16;
      const int mv = fl ? (int)mB[mi] : mI[mi];
      float s = acc[f][r] * INV_SCALE;
      s = mv ? -1e9f : s;
      acc[f][r] = s;
      mx[r] = fmaxf(mx[r], s);
    }
  }
#pragma unroll
  for (int r = 0; r < 4; ++r) {
    mx[r] = fmaxf(mx[r], __shfl_xor(mx[r], 1));
    mx[r] = fmaxf(mx[r], __shfl_xor(mx[r], 2));
    mx[r] = fmaxf(mx[r], __shfl_xor(mx[r], 4));
    mx[r] = fmaxf(mx[r], __shfl_xor(mx[r], 8));
  }
  if (c == 0) {
#pragma unroll
    for (int r = 0; r < 4; ++r) wmax[w][4 * g + r] = mx[r];
  }
  __syncthreads();

  float m_[4], ls[4];
#pragma unroll
  for (int r = 0; r < 4; ++r) {
    const int rr = 4 * g + r;
    m_[r] = fmaxf(fmaxf(wmax[0][rr], wmax[1][rr]), fmaxf(wmax[2][rr], wmax[3][rr]));
    ls[r] = 0.f;
  }
#pragma unroll
  for (int f = 0; f < 16; ++f) {
#pragma unroll
    for (int r = 0; r < 4; ++r) {
      const float e = __expf(acc[f][r] - m_[r]);
      acc[f][r] = e;
      ls[r] += e;
    }
  }
#pragma unroll
  for (int r = 0; r < 4; ++r) {
    ls[r] += __shfl_xor(ls[r], 1);
    ls[r] += __shfl_xor(ls[r], 2);
    ls[r] += __shfl_xor(ls[r], 4);
    ls[r] += __shfl_xor(ls[r], 8);
  }
  if (c == 0) {
#pragma unroll
    for (int r = 0; r < 4; ++r) wsum[w][4 * g + r] = ls[r];
  }
  __syncthreads();

  float inv[4];
#pragma unroll
  for (int r = 0; r < 4; ++r) {
    const int rr = 4 * g + r;
    inv[r] = 1.0f / (wsum[0][rr] + wsum[1][rr] + wsum[2][rr] + wsum[3][rr]);
  }

  // ---- write normalized attn (nontemporal, write-once) + stage P to LDS ----
  size_t obase[4];
#pragma unroll
  for (int r = 0; r < 4; ++r)
    obase[r] = ((size_t)(bh * LQ + q0 + 4 * g + r)) * LQ + k0 + c;
#pragma unroll
  for (int f = 0; f < 16; ++f) {
#pragma unroll
    for (int r = 0; r < 4; ++r) {
      const float e = acc[f][r];
      __builtin_nontemporal_store(e * inv[r], &attn[obase[r] + f * 16]);
      pbuf[w][4 * g + r][f * 16 + c] = f2bf(e);   // unnormalized exp
    }
  }

  // ---- context partial: C2 = P(16x256) @ V(256x64) for this wave's span ----
  f32x4 acc2[4];
#pragma unroll
  for (int cf = 0; cf < 4; ++cf) acc2[cf] = (f32x4){0.f, 0.f, 0.f, 0.f};
#pragma unroll
  for (int ch = 0; ch < 8; ++ch) {
    const bf16x8 ap = *(const bf16x8*)(&pbuf[w][c][ch * 32 + 8 * g]);
#pragma unroll
    for (int cf = 0; cf < 4; ++cf) {
      const ushort_t* vrow = vT + ((size_t)(bh * DH + cf * 16 + c)) * LQ + k0 + ch * 32 + 8 * g;
      const bf16x8 bv = *(const bf16x8*)(vrow);
      acc2[cf] = __builtin_amdgcn_mfma_f32_16x16x32_bf16(ap, bv, acc2[cf], 0, 0, 0);
    }
  }
#pragma unroll
  for (int cf = 0; cf < 4; ++cf) {
#pragma unroll
    for (int r = 0; r < 4; ++r)
      c2s[w][4 * g + r][cf * 16 + c] = acc2[cf][r];
  }
  __syncthreads();

  // ---- sum wave partials, normalize, write context [row][h*64+d] ----
#pragma unroll
  for (int i0 = 0; i0 < 4; ++i0) {
    const int i = t + i0 * 256;
    const int r = i >> 6, d = i & 63;
    const float s = c2s[0][r][d] + c2s[1][r][d] + c2s[2][r][d] + c2s[3][r][d];
    const float iv = 1.0f / (wsum[0][r] + wsum[1][r] + wsum[2][r] + wsum[3][r]);
    ctx[((size_t)(bidx * LQ + q0 + r)) * HT + h * DH + d] = s * iv;
  }
}

// ---------------------------------------------------------------------------
// Output projection + bias + residual + LayerNorm. 16 rows per block.
// NOTE: 16*DM = 304 > 256 threads -> every per-element phase MUST be a
// strided loop (R1 bug: `if (t < 16*DM)` left rows 14-15 uncomputed).
// ---------------------------------------------------------------------------
__global__ __launch_bounds__(256, 4) void k_out(
    const float* __restrict__ ctx, const float* __restrict__ Wo,
    const float* __restrict__ bo, const float* __restrict__ Qin,
    const float* __restrict__ lng, const float* __restrict__ lnb,
    float* __restrict__ out) {
  const int rows0 = blockIdx.x * 16;
  const int t = threadIdx.x;

  __shared__ __align__(16) float cx[16 * HT];
  __shared__ float pre[16][DM + 1];
  __shared__ float mu[16], rs[16];

  const float4* src = (const float4*)(ctx + (size_t)rows0 * HT);
  float4* dst = (float4*)cx;
  for (int i = t; i < 16 * HT / 4; i += 256) dst[i] = src[i];
  __syncthreads();

  for (int i = t; i < 16 * DM; i += 256) {
    const int r = i / DM, j = i % DM;
    float a = bo[j];
    const float* crow = cx + r * HT;
    for (int kk = 0; kk < HT; ++kk) a += crow[kk] * Wo[kk * DM + j];
    a += Qin[(size_t)(rows0 + r) * DM + j];
    pre[r][j] = a;
  }
  __syncthreads();

  if (t < 16) {
    float s = 0.f;
#pragma unroll
    for (int j = 0; j < DM; ++j) s += pre[t][j];
    const float m = s / (float)DM;
    float v = 0.f;
#pragma unroll
    for (int j = 0; j < DM; ++j) { const float d = pre[t][j] - m; v += d * d; }
    v /= (float)DM;
    mu[t] = m;
    rs[t] = rsqrtf(v + 1e-5f);
  }
  __syncthreads();

  for (int i = t; i < 16 * DM; i += 256) {
    const int r = i / DM, j = i % DM;
    out[(size_t)(rows0 + r) * DM + j] = (pre[r][j] - mu[r]) * rs[r] * lng[j] + lnb[j];
  }
}

// ---------------------------------------------------------------------------
extern "C" void kernel_launch(void* const* d_in, const int* in_sizes, int n_in,
                              void* d_out, int out_size, void* d_ws, size_t ws_size,
                              hipStream_t stream) {
  const float* Q  = (const float*)d_in[0];
  const float* K  = (const float*)d_in[1];
  const float* V  = (const float*)d_in[2];
  const void*  mask = d_in[3];
  const float* Wq = (const float*)d_in[4];
  const float* bq = (const float*)d_in[5];
  const float* Wk = (const float*)d_in[6];
  const float* bk = (const float*)d_in[7];
  const float* Wv = (const float*)d_in[8];
  const float* bv = (const float*)d_in[9];
  const float* Wo = (const float*)d_in[10];
  const float* bo = (const float*)d_in[11];
  const float* lng = (const float*)d_in[12];
  const float* lnb = (const float*)d_in[13];

  float* out   = (float*)d_out;
  float* attn  = out + 311296;                 // 16*1024*19
  float* resid = out + 311296 + 134217728;     // + 16*8*1024*1024

  // workspace layout
  ushort_t* qb = (ushort_t*)d_ws;              // 8,388,608 elems = 16 MB
  ushort_t* kb = qb + 8388608;
  ushort_t* vT = kb + 8388608;
  float* ctx   = (float*)((char*)d_ws + 50331648);       // 32 MB
  int* flag    = (int*)((char*)d_ws + 50331648 + 33554432);

  // residual = Q (input), straight D2D copy
  hipMemcpyAsync(resid, Q, (size_t)311296 * sizeof(float),
                 hipMemcpyDeviceToDevice, stream);

  k_detect<<<1, 256, 0, stream>>>((const unsigned char*)mask, flag);
  k_proj<<<2048, 256, 0, stream>>>(Q, K, V, Wq, bq, Wk, bk, Wv, bv, qb, kb, vT);
  k_attn<<<8192, 256, 0, stream>>>(qb, kb, vT, mask, flag, attn, ctx);
  k_out<<<1024, 256, 0, stream>>>(ctx, Wo, bo, Q, lng, lnb, out);
}